// Round 4
// baseline (201.168 us; speedup 1.0000x reference)
//
#include <hip/hip_runtime.h>
#include <stdint.h>

// YOLO loss R4: no LDS, no barriers. One cell per thread, direct strided
// vector loads into VGPRs. The per-cell records (120 B pred / 100 B target)
// are contiguous across a wave, so every 64B line is fully consumed via L1 —
// zero wasted HBM bytes. Occupancy is VGPR-bound (~24-32 waves/CU vs 5-11 in
// the LDS-staged versions); latency hidden by wave count + compiler's
// fine-grained vmcnt on register loads.

#define NCLS 20
#define SLOTS 128
#define BLOCKS 3136          // 802816 cells / 256 threads

typedef float f4 __attribute__((ext_vector_type(4), aligned(4)));
typedef float f2 __attribute__((ext_vector_type(2), aligned(4)));

__device__ static inline f4 ld4(const float* p) { return *(const f4*)p; }
__device__ static inline f2 ld2(const float* p) { return *(const f2*)p; }

__global__ __launch_bounds__(256) void yolo_main(
    const float* __restrict__ pred,
    const float* __restrict__ target,
    float* __restrict__ ws)
{
    __shared__ float wave_sums[4];

    const int tid  = blockIdx.x * 256 + threadIdx.x;  // == cell index, exact fit
    const int lane = threadIdx.x & 63;
    const int wave = threadIdx.x >> 6;

    const float* p = pred   + (size_t)tid * 30;
    const float* t = target + (size_t)tid * 25;

    // ---- load whole records (8 + 7 vmem instructions, all independent)
    f4 pc0 = ld4(p +  0);  f4 pc1 = ld4(p +  4);  f4 pc2 = ld4(p +  8);
    f4 pc3 = ld4(p + 12);  f4 pc4 = ld4(p + 16);
    f4 pb0 = ld4(p + 20);  // conf0, x0, y0, w0
    f4 pb1 = ld4(p + 24);  // h0, conf1, x1, y1
    f2 pb2 = ld2(p + 28);  // w1, h1

    f4 tc0 = ld4(t +  0);  f4 tc1 = ld4(t +  4);  f4 tc2 = ld4(t +  8);
    f4 tc3 = ld4(t + 12);  f4 tc4 = ld4(t + 16);
    f4 tb  = ld4(t + 20);  // tobj, tx, ty, tw
    const float th = t[24];

    const float EPS = 1e-6f;

    const float tobj = tb.x;
    const float tx = tb.y, ty = tb.z, tw = tb.w;

    const float t_x1 = tx - tw * 0.5f, t_x2 = tx + tw * 0.5f;
    const float t_y1 = ty - th * 0.5f, t_y2 = ty + th * 0.5f;
    const float t_area = fabsf((t_x2 - t_x1) * (t_y2 - t_y1));

    // box fields: [conf, x, y, w, h] per box
    const float conf0 = pb0.x, x0v = pb0.y, y0v = pb0.z, w0v = pb0.w, h0v = pb1.x;
    const float conf1 = pb1.y, x1v = pb1.z, y1v = pb1.w, w1v = pb2.x, h1v = pb2.y;

    float iou[2];
    {
        const float bx[2] = {x0v, x1v}, by[2] = {y0v, y1v};
        const float bw[2] = {w0v, w1v}, bh[2] = {h0v, h1v};
        #pragma unroll
        for (int b = 0; b < 2; ++b) {
            const float x1 = bx[b] - bw[b] * 0.5f, x2 = bx[b] + bw[b] * 0.5f;
            const float y1 = by[b] - bh[b] * 0.5f, y2 = by[b] + bh[b] * 0.5f;
            const float iw = fmaxf(fminf(x2, t_x2) - fmaxf(x1, t_x1), 0.0f);
            const float ih = fmaxf(fminf(y2, t_y2) - fmaxf(y1, t_y1), 0.0f);
            const float inter = iw * ih;
            const float a1 = fabsf((x2 - x1) * (y2 - y1));
            iou[b] = inter / (a1 + t_area - inter + EPS);
        }
    }
    const bool take1 = (iou[1] > iou[0]);   // jnp.argmax first-max tie-break

    const float bconf = take1 ? conf1 : conf0;
    const float bxv   = take1 ? x1v   : x0v;
    const float byv   = take1 ? y1v   : y0v;
    const float bwv   = take1 ? w1v   : w0v;
    const float bhv   = take1 ? h1v   : h0v;

    const float sgnw = (bwv > 0.f) ? 1.f : ((bwv < 0.f) ? -1.f : 0.f);
    const float sgnh = (bhv > 0.f) ? 1.f : ((bhv < 0.f) ? -1.f : 0.f);
    const float swv = sgnw * sqrtf(fabsf(bwv) + EPS);
    const float shv = sgnh * sqrtf(fabsf(bhv) + EPS);

    float d0 = tobj * bxv - tobj * tx;
    float d1 = tobj * byv - tobj * ty;
    float d2 = tobj * swv - sqrtf(fmaxf(tobj * tw, 0.0f));
    float d3 = tobj * shv - sqrtf(fmaxf(tobj * th, 0.0f));
    float box_loss = d0 * d0 + d1 * d1 + d2 * d2 + d3 * d3;

    const float noobj = 1.0f - tobj;
    float n0 = noobj * (conf0 - tobj);
    float n1 = noobj * (conf1 - tobj);
    float no_object_loss = n0 * n0 + n1 * n1;

    float od = tobj * (bconf - tobj);
    float object_loss = od * od;

    float class_loss = 0.0f;
    {
        const f4 pc[5] = {pc0, pc1, pc2, pc3, pc4};
        const f4 tc[5] = {tc0, tc1, tc2, tc3, tc4};
        #pragma unroll
        for (int v = 0; v < 5; ++v) {
            #pragma unroll
            for (int k = 0; k < 4; ++k) {
                float cd = tobj * (pc[v][k] - tc[v][k]);
                class_loss += cd * cd;
            }
        }
    }

    float loss = 5.0f * box_loss + object_loss + 0.5f * no_object_loss + class_loss;

    // ---- wave shuffle reduce -> cross-wave LDS -> one spread atomic per block
    #pragma unroll
    for (int off = 32; off > 0; off >>= 1)
        loss += __shfl_down(loss, off, 64);

    if (lane == 0) wave_sums[wave] = loss;
    __syncthreads();
    if (threadIdx.x == 0) {
        float s = wave_sums[0] + wave_sums[1] + wave_sums[2] + wave_sums[3];
        atomicAdd(&ws[blockIdx.x & (SLOTS - 1)], s);
    }
}

__global__ __launch_bounds__(64) void yolo_reduce(
    const float* __restrict__ ws, float* __restrict__ out)
{
    const int lane = threadIdx.x;
    float s = ws[lane] + ws[lane + 64];
    #pragma unroll
    for (int off = 32; off > 0; off >>= 1)
        s += __shfl_down(s, off, 64);
    if (lane == 0) out[0] = s;
}

extern "C" void kernel_launch(void* const* d_in, const int* in_sizes, int n_in,
                              void* d_out, int out_size, void* d_ws, size_t ws_size,
                              hipStream_t stream) {
    const float* pred   = (const float*)d_in[0];
    const float* target = (const float*)d_in[1];
    float* ws  = (float*)d_ws;
    float* out = (float*)d_out;

    hipMemsetAsync(ws, 0, SLOTS * sizeof(float), stream);

    hipLaunchKernelGGL(yolo_main, dim3(BLOCKS), dim3(256), 0, stream,
                       pred, target, ws);
    hipLaunchKernelGGL(yolo_reduce, dim3(1), dim3(64), 0, stream, ws, out);
}

// Round 5
// 195.848 us; speedup vs baseline: 1.0272x; 1.0272x over previous
//
#include <hip/hip_runtime.h>
#include <stdint.h>

// YOLO loss R5: persistent single-wave blocks, zero barriers.
// Coalesced float4 loads -> registers (14 x 1KB per wave per tile, all in
// flight while computing the previous tile), register -> LDS bounce for the
// per-cell transpose, LDS 14080 B/block -> 11 waves/CU.
// Pipeline: write LDS(t) from regs, issue loads(t+1), compute(t) from LDS.

#define NCLS 20
#define SLOTS 128
#define GRID 2816            // 11 blocks/CU * 256 CUs
#define TILES 12544          // 802816 cells / 64 cells per tile

typedef float f4 __attribute__((ext_vector_type(4)));  // 16B aligned

__device__ static inline f4 ldg4(const float* p) { return *(const f4*)p; }

__global__ __launch_bounds__(64) void yolo_main(
    const float* __restrict__ pred,
    const float* __restrict__ target,
    float* __restrict__ ws)
{
    __shared__ float sp[64 * 30];  // 7680 B
    __shared__ float st[64 * 25];  // 6400 B

    const int lane = threadIdx.x;
    const int blk  = blockIdx.x;
    const int n = (TILES - blk + GRID - 1) / GRID;   // 4 or 5 tiles

    const float EPS = 1e-6f;

    f4 rp0, rp1, rp2, rp3, rp4, rp5, rp6, rp7;  // pred: 7.5 rounds of 64xf4
    f4 rt0, rt1, rt2, rt3, rt4, rt5, rt6;       // target: 6.25 rounds

    // ---- issue loads for tile 0
    {
        const float* gp = pred   + (size_t)blk * 1920;
        const float* gt = target + (size_t)blk * 1600;
        rp0 = ldg4(gp + lane * 4 + 0 * 256);
        rp1 = ldg4(gp + lane * 4 + 1 * 256);
        rp2 = ldg4(gp + lane * 4 + 2 * 256);
        rp3 = ldg4(gp + lane * 4 + 3 * 256);
        rp4 = ldg4(gp + lane * 4 + 4 * 256);
        rp5 = ldg4(gp + lane * 4 + 5 * 256);
        rp6 = ldg4(gp + lane * 4 + 6 * 256);
        if (lane < 32) rp7 = ldg4(gp + lane * 4 + 7 * 256);
        rt0 = ldg4(gt + lane * 4 + 0 * 256);
        rt1 = ldg4(gt + lane * 4 + 1 * 256);
        rt2 = ldg4(gt + lane * 4 + 2 * 256);
        rt3 = ldg4(gt + lane * 4 + 3 * 256);
        rt4 = ldg4(gt + lane * 4 + 4 * 256);
        rt5 = ldg4(gt + lane * 4 + 5 * 256);
        if (lane < 16) rt6 = ldg4(gt + lane * 4 + 6 * 256);
    }

    float acc = 0.0f;

    for (int i = 0; i < n; ++i) {
        // ---- regs -> LDS (compiler inserts the vmcnt waits at first use)
        *(f4*)(sp + lane * 4 + 0 * 256) = rp0;
        *(f4*)(sp + lane * 4 + 1 * 256) = rp1;
        *(f4*)(sp + lane * 4 + 2 * 256) = rp2;
        *(f4*)(sp + lane * 4 + 3 * 256) = rp3;
        *(f4*)(sp + lane * 4 + 4 * 256) = rp4;
        *(f4*)(sp + lane * 4 + 5 * 256) = rp5;
        *(f4*)(sp + lane * 4 + 6 * 256) = rp6;
        if (lane < 32) *(f4*)(sp + lane * 4 + 7 * 256) = rp7;
        *(f4*)(st + lane * 4 + 0 * 256) = rt0;
        *(f4*)(st + lane * 4 + 1 * 256) = rt1;
        *(f4*)(st + lane * 4 + 2 * 256) = rt2;
        *(f4*)(st + lane * 4 + 3 * 256) = rt3;
        *(f4*)(st + lane * 4 + 4 * 256) = rt4;
        *(f4*)(st + lane * 4 + 5 * 256) = rt5;
        if (lane < 16) *(f4*)(st + lane * 4 + 6 * 256) = rt6;

        // ---- issue loads for tile i+1 (in flight during compute below)
        if (i + 1 < n) {
            const int tile = blk + (i + 1) * GRID;
            const float* gp = pred   + (size_t)tile * 1920;
            const float* gt = target + (size_t)tile * 1600;
            rp0 = ldg4(gp + lane * 4 + 0 * 256);
            rp1 = ldg4(gp + lane * 4 + 1 * 256);
            rp2 = ldg4(gp + lane * 4 + 2 * 256);
            rp3 = ldg4(gp + lane * 4 + 3 * 256);
            rp4 = ldg4(gp + lane * 4 + 4 * 256);
            rp5 = ldg4(gp + lane * 4 + 5 * 256);
            rp6 = ldg4(gp + lane * 4 + 6 * 256);
            if (lane < 32) rp7 = ldg4(gp + lane * 4 + 7 * 256);
            rt0 = ldg4(gt + lane * 4 + 0 * 256);
            rt1 = ldg4(gt + lane * 4 + 1 * 256);
            rt2 = ldg4(gt + lane * 4 + 2 * 256);
            rt3 = ldg4(gt + lane * 4 + 3 * 256);
            rt4 = ldg4(gt + lane * 4 + 4 * 256);
            rt5 = ldg4(gt + lane * 4 + 5 * 256);
            if (lane < 16) rt6 = ldg4(gt + lane * 4 + 6 * 256);
        }

        // ---- compute this wave's 64 cells from LDS (wave-private, no barrier)
        const float* lp = sp + lane * 30;
        const float* lt = st + lane * 25;

        const float tobj = lt[20];
        const float tx = lt[21], ty = lt[22], tw = lt[23], th = lt[24];

        const float t_x1 = tx - tw * 0.5f, t_x2 = tx + tw * 0.5f;
        const float t_y1 = ty - th * 0.5f, t_y2 = ty + th * 0.5f;
        const float t_area = fabsf((t_x2 - t_x1) * (t_y2 - t_y1));

        float iou[2];
        #pragma unroll
        for (int b = 0; b < 2; ++b) {
            const float bx = lp[NCLS + 5 * b + 1];
            const float by = lp[NCLS + 5 * b + 2];
            const float bw = lp[NCLS + 5 * b + 3];
            const float bh = lp[NCLS + 5 * b + 4];
            const float x1 = bx - bw * 0.5f, x2 = bx + bw * 0.5f;
            const float y1 = by - bh * 0.5f, y2 = by + bh * 0.5f;
            const float iw = fmaxf(fminf(x2, t_x2) - fmaxf(x1, t_x1), 0.0f);
            const float ih = fmaxf(fminf(y2, t_y2) - fmaxf(y1, t_y1), 0.0f);
            const float inter = iw * ih;
            const float a1 = fabsf((x2 - x1) * (y2 - y1));
            iou[b] = inter / (a1 + t_area - inter + EPS);
        }
        const int best = (iou[1] > iou[0]) ? 1 : 0;

        const float bconf = lp[NCLS + 5 * best + 0];
        const float bxv   = lp[NCLS + 5 * best + 1];
        const float byv   = lp[NCLS + 5 * best + 2];
        const float bwv   = lp[NCLS + 5 * best + 3];
        const float bhv   = lp[NCLS + 5 * best + 4];

        const float sgnw = (bwv > 0.f) ? 1.f : ((bwv < 0.f) ? -1.f : 0.f);
        const float sgnh = (bhv > 0.f) ? 1.f : ((bhv < 0.f) ? -1.f : 0.f);
        const float swv = sgnw * sqrtf(fabsf(bwv) + EPS);
        const float shv = sgnh * sqrtf(fabsf(bhv) + EPS);

        float d0 = tobj * bxv - tobj * tx;
        float d1 = tobj * byv - tobj * ty;
        float d2 = tobj * swv - sqrtf(fmaxf(tobj * tw, 0.0f));
        float d3 = tobj * shv - sqrtf(fmaxf(tobj * th, 0.0f));
        float box_loss = d0 * d0 + d1 * d1 + d2 * d2 + d3 * d3;

        const float noobj = 1.0f - tobj;
        float n0 = noobj * (lp[NCLS + 0] - tobj);
        float n1 = noobj * (lp[NCLS + 5] - tobj);
        float no_object_loss = n0 * n0 + n1 * n1;

        float od = tobj * (bconf - tobj);
        float object_loss = od * od;

        float class_loss = 0.0f;
        #pragma unroll
        for (int k = 0; k < NCLS; ++k) {
            float cd = tobj * (lp[k] - lt[k]);
            class_loss += cd * cd;
        }

        acc += 5.0f * box_loss + object_loss + 0.5f * no_object_loss + class_loss;

        __asm__ volatile("" ::: "memory");  // keep LDS reads inside this iter
    }

    // wave reduce + one spread atomic per wave
    #pragma unroll
    for (int off = 32; off > 0; off >>= 1)
        acc += __shfl_down(acc, off, 64);

    if (lane == 0)
        atomicAdd(&ws[blk & (SLOTS - 1)], acc);
}

__global__ __launch_bounds__(64) void yolo_reduce(
    const float* __restrict__ ws, float* __restrict__ out)
{
    const int lane = threadIdx.x;
    float s = ws[lane] + ws[lane + 64];
    #pragma unroll
    for (int off = 32; off > 0; off >>= 1)
        s += __shfl_down(s, off, 64);
    if (lane == 0) out[0] = s;
}

extern "C" void kernel_launch(void* const* d_in, const int* in_sizes, int n_in,
                              void* d_out, int out_size, void* d_ws, size_t ws_size,
                              hipStream_t stream) {
    const float* pred   = (const float*)d_in[0];
    const float* target = (const float*)d_in[1];
    float* ws  = (float*)d_ws;
    float* out = (float*)d_out;

    hipMemsetAsync(ws, 0, SLOTS * sizeof(float), stream);

    hipLaunchKernelGGL(yolo_main, dim3(GRID), dim3(64), 0, stream,
                       pred, target, ws);
    hipLaunchKernelGGL(yolo_reduce, dim3(1), dim3(64), 0, stream, ws, out);
}

// Round 6
// 181.691 us; speedup vs baseline: 1.1072x; 1.0779x over previous
//
#include <hip/hip_runtime.h>
#include <stdint.h>

// YOLO loss R6: R5 (persistent single-wave blocks, coalesced f4->reg->LDS,
// one-tile-ahead pipeline, zero barriers) + NON-TEMPORAL global loads.
// Theory: 5 structurally disjoint designs all pin at ~2.7 TB/s delivered,
// insensitive to occupancy/coalescing/source(HBM vs L3) -> suspect L1
// allocation/miss-tracking pressure from 177MB read-once traffic. nt loads
// bypass L1 allocation; clean A/B against R5's 66 us.

#define NCLS 20
#define SLOTS 128
#define GRID 2816            // target ~11 blocks/CU at 14336 B LDS
#define TILES 12544          // 802816 cells / 64 cells per tile

typedef float f4 __attribute__((ext_vector_type(4)));  // 16B aligned

__device__ static inline f4 ldg4nt(const float* p) {
    return __builtin_nontemporal_load((const f4*)p);
}

__global__ __launch_bounds__(64) void yolo_main(
    const float* __restrict__ pred,
    const float* __restrict__ target,
    float* __restrict__ ws)
{
    __shared__ float sp[64 * 30];  // 7680 B
    __shared__ float st[64 * 25];  // 6400 B

    const int lane = threadIdx.x;
    const int blk  = blockIdx.x;
    const int n = (TILES - blk + GRID - 1) / GRID;   // 4 or 5 tiles

    const float EPS = 1e-6f;

    f4 rp0, rp1, rp2, rp3, rp4, rp5, rp6, rp7;
    f4 rt0, rt1, rt2, rt3, rt4, rt5, rt6;

    // ---- issue loads for tile 0 (non-temporal: no L1 allocation)
    {
        const float* gp = pred   + (size_t)blk * 1920;
        const float* gt = target + (size_t)blk * 1600;
        rp0 = ldg4nt(gp + lane * 4 + 0 * 256);
        rp1 = ldg4nt(gp + lane * 4 + 1 * 256);
        rp2 = ldg4nt(gp + lane * 4 + 2 * 256);
        rp3 = ldg4nt(gp + lane * 4 + 3 * 256);
        rp4 = ldg4nt(gp + lane * 4 + 4 * 256);
        rp5 = ldg4nt(gp + lane * 4 + 5 * 256);
        rp6 = ldg4nt(gp + lane * 4 + 6 * 256);
        if (lane < 32) rp7 = ldg4nt(gp + lane * 4 + 7 * 256);
        rt0 = ldg4nt(gt + lane * 4 + 0 * 256);
        rt1 = ldg4nt(gt + lane * 4 + 1 * 256);
        rt2 = ldg4nt(gt + lane * 4 + 2 * 256);
        rt3 = ldg4nt(gt + lane * 4 + 3 * 256);
        rt4 = ldg4nt(gt + lane * 4 + 4 * 256);
        rt5 = ldg4nt(gt + lane * 4 + 5 * 256);
        if (lane < 16) rt6 = ldg4nt(gt + lane * 4 + 6 * 256);
    }

    float acc = 0.0f;

    for (int i = 0; i < n; ++i) {
        // ---- regs -> LDS (compiler inserts vmcnt waits at first use)
        *(f4*)(sp + lane * 4 + 0 * 256) = rp0;
        *(f4*)(sp + lane * 4 + 1 * 256) = rp1;
        *(f4*)(sp + lane * 4 + 2 * 256) = rp2;
        *(f4*)(sp + lane * 4 + 3 * 256) = rp3;
        *(f4*)(sp + lane * 4 + 4 * 256) = rp4;
        *(f4*)(sp + lane * 4 + 5 * 256) = rp5;
        *(f4*)(sp + lane * 4 + 6 * 256) = rp6;
        if (lane < 32) *(f4*)(sp + lane * 4 + 7 * 256) = rp7;
        *(f4*)(st + lane * 4 + 0 * 256) = rt0;
        *(f4*)(st + lane * 4 + 1 * 256) = rt1;
        *(f4*)(st + lane * 4 + 2 * 256) = rt2;
        *(f4*)(st + lane * 4 + 3 * 256) = rt3;
        *(f4*)(st + lane * 4 + 4 * 256) = rt4;
        *(f4*)(st + lane * 4 + 5 * 256) = rt5;
        if (lane < 16) *(f4*)(st + lane * 4 + 6 * 256) = rt6;

        // ---- issue loads for tile i+1 (in flight during compute below)
        if (i + 1 < n) {
            const int tile = blk + (i + 1) * GRID;
            const float* gp = pred   + (size_t)tile * 1920;
            const float* gt = target + (size_t)tile * 1600;
            rp0 = ldg4nt(gp + lane * 4 + 0 * 256);
            rp1 = ldg4nt(gp + lane * 4 + 1 * 256);
            rp2 = ldg4nt(gp + lane * 4 + 2 * 256);
            rp3 = ldg4nt(gp + lane * 4 + 3 * 256);
            rp4 = ldg4nt(gp + lane * 4 + 4 * 256);
            rp5 = ldg4nt(gp + lane * 4 + 5 * 256);
            rp6 = ldg4nt(gp + lane * 4 + 6 * 256);
            if (lane < 32) rp7 = ldg4nt(gp + lane * 4 + 7 * 256);
            rt0 = ldg4nt(gt + lane * 4 + 0 * 256);
            rt1 = ldg4nt(gt + lane * 4 + 1 * 256);
            rt2 = ldg4nt(gt + lane * 4 + 2 * 256);
            rt3 = ldg4nt(gt + lane * 4 + 3 * 256);
            rt4 = ldg4nt(gt + lane * 4 + 4 * 256);
            rt5 = ldg4nt(gt + lane * 4 + 5 * 256);
            if (lane < 16) rt6 = ldg4nt(gt + lane * 4 + 6 * 256);
        }

        // ---- compute this wave's 64 cells from LDS (wave-private)
        const float* lp = sp + lane * 30;
        const float* lt = st + lane * 25;

        const float tobj = lt[20];
        const float tx = lt[21], ty = lt[22], tw = lt[23], th = lt[24];

        const float t_x1 = tx - tw * 0.5f, t_x2 = tx + tw * 0.5f;
        const float t_y1 = ty - th * 0.5f, t_y2 = ty + th * 0.5f;
        const float t_area = fabsf((t_x2 - t_x1) * (t_y2 - t_y1));

        float iou[2];
        #pragma unroll
        for (int b = 0; b < 2; ++b) {
            const float bx = lp[NCLS + 5 * b + 1];
            const float by = lp[NCLS + 5 * b + 2];
            const float bw = lp[NCLS + 5 * b + 3];
            const float bh = lp[NCLS + 5 * b + 4];
            const float x1 = bx - bw * 0.5f, x2 = bx + bw * 0.5f;
            const float y1 = by - bh * 0.5f, y2 = by + bh * 0.5f;
            const float iw = fmaxf(fminf(x2, t_x2) - fmaxf(x1, t_x1), 0.0f);
            const float ih = fmaxf(fminf(y2, t_y2) - fmaxf(y1, t_y1), 0.0f);
            const float inter = iw * ih;
            const float a1 = fabsf((x2 - x1) * (y2 - y1));
            iou[b] = inter / (a1 + t_area - inter + EPS);
        }
        const int best = (iou[1] > iou[0]) ? 1 : 0;

        const float bconf = lp[NCLS + 5 * best + 0];
        const float bxv   = lp[NCLS + 5 * best + 1];
        const float byv   = lp[NCLS + 5 * best + 2];
        const float bwv   = lp[NCLS + 5 * best + 3];
        const float bhv   = lp[NCLS + 5 * best + 4];

        const float sgnw = (bwv > 0.f) ? 1.f : ((bwv < 0.f) ? -1.f : 0.f);
        const float sgnh = (bhv > 0.f) ? 1.f : ((bhv < 0.f) ? -1.f : 0.f);
        const float swv = sgnw * sqrtf(fabsf(bwv) + EPS);
        const float shv = sgnh * sqrtf(fabsf(bhv) + EPS);

        float d0 = tobj * bxv - tobj * tx;
        float d1 = tobj * byv - tobj * ty;
        float d2 = tobj * swv - sqrtf(fmaxf(tobj * tw, 0.0f));
        float d3 = tobj * shv - sqrtf(fmaxf(tobj * th, 0.0f));
        float box_loss = d0 * d0 + d1 * d1 + d2 * d2 + d3 * d3;

        const float noobj = 1.0f - tobj;
        float n0 = noobj * (lp[NCLS + 0] - tobj);
        float n1 = noobj * (lp[NCLS + 5] - tobj);
        float no_object_loss = n0 * n0 + n1 * n1;

        float od = tobj * (bconf - tobj);
        float object_loss = od * od;

        float class_loss = 0.0f;
        #pragma unroll
        for (int k = 0; k < NCLS; ++k) {
            float cd = tobj * (lp[k] - lt[k]);
            class_loss += cd * cd;
        }

        acc += 5.0f * box_loss + object_loss + 0.5f * no_object_loss + class_loss;

        __asm__ volatile("" ::: "memory");  // keep LDS reads inside this iter
    }

    // wave reduce + one spread atomic per wave
    #pragma unroll
    for (int off = 32; off > 0; off >>= 1)
        acc += __shfl_down(acc, off, 64);

    if (lane == 0)
        atomicAdd(&ws[blk & (SLOTS - 1)], acc);
}

__global__ __launch_bounds__(64) void yolo_reduce(
    const float* __restrict__ ws, float* __restrict__ out)
{
    const int lane = threadIdx.x;
    float s = ws[lane] + ws[lane + 64];
    #pragma unroll
    for (int off = 32; off > 0; off >>= 1)
        s += __shfl_down(s, off, 64);
    if (lane == 0) out[0] = s;
}

extern "C" void kernel_launch(void* const* d_in, const int* in_sizes, int n_in,
                              void* d_out, int out_size, void* d_ws, size_t ws_size,
                              hipStream_t stream) {
    const float* pred   = (const float*)d_in[0];
    const float* target = (const float*)d_in[1];
    float* ws  = (float*)d_ws;
    float* out = (float*)d_out;

    hipMemsetAsync(ws, 0, SLOTS * sizeof(float), stream);

    hipLaunchKernelGGL(yolo_main, dim3(GRID), dim3(64), 0, stream,
                       pred, target, ws);
    hipLaunchKernelGGL(yolo_reduce, dim3(1), dim3(64), 0, stream, ws, out);
}